// Round 1
// baseline (531.998 us; speedup 1.0000x reference)
//
#include <hip/hip_runtime.h>

typedef __bf16 bf16_t;
typedef __bf16 bf16x8 __attribute__((ext_vector_type(8)));
typedef __bf16 bf16x4 __attribute__((ext_vector_type(4)));
typedef __bf16 bf16x2 __attribute__((ext_vector_type(2)));
typedef float f32x4 __attribute__((ext_vector_type(4)));

#define NB 8
#define SQ 2048
#define SK 2048
#define DD 512

#define BM 128
#define BN 128
#define BK 32
#define LDK 40   // padded LDS row stride (80 B, 16B-aligned rows for b128)
#define NBLK (SK / BN)   // n-blocks per row = softmax partial count

// ------------------------------------------------- logits = (2 q.k - k^2)/T
// bf16 hi/lo split GEMM (fp32 accum, ~2^-17 rel). q^2 row term is
// softmax-invariant and dropped. NEW: epilogue also emits per-(row, n-block)
// softmax partials (tile max m_i, tile sum s_i = sum exp(s - m_i)) so the
// standalone 268 MB softmax pass can be eliminated entirely.
__global__ __launch_bounds__(256, 2) void logits_kernel(
    const float* __restrict__ Q, const float* __restrict__ K,
    const float* __restrict__ tempP, float* __restrict__ logits,
    float* __restrict__ Mpart, float* __restrict__ Spart) {
  __shared__ bf16_t qh[BM][LDK], ql[BM][LDK], kh[BN][LDK], kl[BN][LDK];
  __shared__ float ksred[BN][8];
  __shared__ float mred[BM][2], sred[BM][2];
  const int b = blockIdx.z;
  const int m0 = blockIdx.y * BM;
  const int n0 = blockIdx.x * BN;
  const int tid = threadIdx.x;
  const int lane = tid & 63;
  const int wave = tid >> 6;
  const int wm = (wave >> 1) * 64;
  const int wn = (wave & 1) * 64;
  const int lrow = lane & 15;
  const int quad = lane >> 4;

  const float* Qb = Q + (size_t)b * SQ * DD;
  const float* Kb = K + (size_t)b * SK * DD;

  const int srow = tid >> 3;        // 0..31
  const int scol = (tid & 7) * 4;   // 0,4,...,28

  const float* qbase = Qb + (size_t)(m0 + srow) * DD + scol;
  const float* kbase = Kb + (size_t)(n0 + srow) * DD + scol;

  f32x4 acc[4][4];
#pragma unroll
  for (int i = 0; i < 4; i++)
#pragma unroll
    for (int j = 0; j < 4; j++) acc[i][j] = (f32x4){0.f, 0.f, 0.f, 0.f};

  float kss[4] = {0.f, 0.f, 0.f, 0.f};

  float4 pq[4], pk[4];
#pragma unroll
  for (int i = 0; i < 4; i++) {
    pq[i] = *(const float4*)(qbase + (size_t)i * 32 * DD);
    pk[i] = *(const float4*)(kbase + (size_t)i * 32 * DD);
  }

  for (int k0 = 0; k0 < DD; k0 += BK) {
    __syncthreads();  // previous iteration's LDS reads complete
    // ---- convert + LDS store (consumes prefetch regs)
#pragma unroll
    for (int i = 0; i < 4; i++) {
      const int r = srow + i * 32;
      float4 qv = pq[i], kv = pk[i];
      bf16_t q0 = (bf16_t)qv.x, q1 = (bf16_t)qv.y, q2 = (bf16_t)qv.z, q3 = (bf16_t)qv.w;
      bf16x4 qhv = {q0, q1, q2, q3};
      bf16x4 qlv = {(bf16_t)(qv.x - (float)q0), (bf16_t)(qv.y - (float)q1),
                    (bf16_t)(qv.z - (float)q2), (bf16_t)(qv.w - (float)q3)};
      bf16_t c0 = (bf16_t)kv.x, c1 = (bf16_t)kv.y, c2 = (bf16_t)kv.z, c3 = (bf16_t)kv.w;
      bf16x4 khv = {c0, c1, c2, c3};
      bf16x4 klv = {(bf16_t)(kv.x - (float)c0), (bf16_t)(kv.y - (float)c1),
                    (bf16_t)(kv.z - (float)c2), (bf16_t)(kv.w - (float)c3)};
      *(bf16x4*)&qh[r][scol] = qhv;
      *(bf16x4*)&ql[r][scol] = qlv;
      *(bf16x4*)&kh[r][scol] = khv;
      *(bf16x4*)&kl[r][scol] = klv;
      kss[i] = fmaf(kv.x, kv.x, kss[i]);
      kss[i] = fmaf(kv.y, kv.y, kss[i]);
      kss[i] = fmaf(kv.z, kv.z, kss[i]);
      kss[i] = fmaf(kv.w, kv.w, kss[i]);
    }
    __syncthreads();

    // ---- prefetch next tile (global reads only; hide under MFMA)
    if (k0 + BK < DD) {
#pragma unroll
      for (int i = 0; i < 4; i++) {
        pq[i] = *(const float4*)(qbase + (size_t)i * 32 * DD + (k0 + BK));
        pk[i] = *(const float4*)(kbase + (size_t)i * 32 * DD + (k0 + BK));
      }
    }

    // ---- MFMA phase
    bf16x8 bh[4], bl[4];
#pragma unroll
    for (int ni = 0; ni < 4; ni++) {
      bh[ni] = *(const bf16x8*)&kh[wn + ni * 16 + lrow][quad * 8];
      bl[ni] = *(const bf16x8*)&kl[wn + ni * 16 + lrow][quad * 8];
    }
#pragma unroll
    for (int mi = 0; mi < 4; mi++) {
      bf16x8 ah = *(const bf16x8*)&qh[wm + mi * 16 + lrow][quad * 8];
      bf16x8 al = *(const bf16x8*)&ql[wm + mi * 16 + lrow][quad * 8];
#pragma unroll
      for (int ni = 0; ni < 4; ni++) {
        acc[mi][ni] = __builtin_amdgcn_mfma_f32_16x16x32_bf16(ah, bh[ni], acc[mi][ni], 0, 0, 0);
        acc[mi][ni] = __builtin_amdgcn_mfma_f32_16x16x32_bf16(ah, bl[ni], acc[mi][ni], 0, 0, 0);
        acc[mi][ni] = __builtin_amdgcn_mfma_f32_16x16x32_bf16(al, bh[ni], acc[mi][ni], 0, 0, 0);
      }
    }
  }

  // ---- k^2 reduction (separate LDS buffer)
#pragma unroll
  for (int i = 0; i < 4; i++) ksred[srow + i * 32][tid & 7] = kss[i];
  __syncthreads();

  const float invT = 1.0f / tempP[0];
  float* Lb = logits + (size_t)b * SQ * SK;
  float ks4[4];
#pragma unroll
  for (int ni = 0; ni < 4; ni++) {
    const float* kr = ksred[wn + ni * 16 + lrow];
    ks4[ni] = ((kr[0] + kr[1]) + (kr[2] + kr[3])) +
              ((kr[4] + kr[5]) + (kr[6] + kr[7]));
  }

  // ---- store raw logits + per-row tile softmax stats.
  // Per (mi,r) the 16 lanes of a quad jointly cover this wave's 64 columns
  // (4 ni x 16 lrow); shfl_xor {1,2,4,8} stays inside the quad group.
#pragma unroll
  for (int mi = 0; mi < 4; mi++) {
#pragma unroll
    for (int r = 0; r < 4; r++) {
      const int row = wm + mi * 16 + quad * 4 + r;  // block-local row
      float sv[4];
#pragma unroll
      for (int ni = 0; ni < 4; ni++) {
        sv[ni] = (2.0f * acc[mi][ni][r] - ks4[ni]) * invT;
        Lb[(size_t)(m0 + row) * SK + (n0 + wn + ni * 16 + lrow)] = sv[ni];
      }
      float rm = fmaxf(fmaxf(sv[0], sv[1]), fmaxf(sv[2], sv[3]));
      rm = fmaxf(rm, __shfl_xor(rm, 1));
      rm = fmaxf(rm, __shfl_xor(rm, 2));
      rm = fmaxf(rm, __shfl_xor(rm, 4));
      rm = fmaxf(rm, __shfl_xor(rm, 8));
      float rs = __expf(sv[0] - rm) + __expf(sv[1] - rm) +
                 __expf(sv[2] - rm) + __expf(sv[3] - rm);
      rs += __shfl_xor(rs, 1);
      rs += __shfl_xor(rs, 2);
      rs += __shfl_xor(rs, 4);
      rs += __shfl_xor(rs, 8);
      if (lrow == 0) {
        mred[row][wave & 1] = rm;
        sred[row][wave & 1] = rs;
      }
    }
  }
  __syncthreads();
  if (tid < BM) {
    const float ma = mred[tid][0], mb = mred[tid][1];
    const float M = fmaxf(ma, mb);
    const float S = sred[tid][0] * __expf(ma - M) + sred[tid][1] * __expf(mb - M);
    const size_t o = ((size_t)b * NBLK + blockIdx.x) * SQ + (m0 + tid);
    Mpart[o] = M;
    Spart[o] = S;
  }
}

// ------------------------------------------------- fused softmax + O = W @ V
// One block owns PM=64 query rows x ALL D=512 (512 threads, 8 waves), so:
//  - each raw-logit row-panel is read exactly ONCE (no x4 D-split dup),
//  - normalized weights are written back IN PLACE from the registers that
//    hold the raw values (single-owner, race-free),
//  - softmax stats come from the logits kernel's partials (split-softmax
//    combine in the prologue) -> the 268 MB softmax pass is gone.
#define PM 64

__global__ __launch_bounds__(512, 2) void pv_kernel(
    float* __restrict__ L,               // raw logits in, weights out (in place)
    const float* __restrict__ V,
    const float* __restrict__ Mpart, const float* __restrict__ Spart,
    float* __restrict__ O) {
  __shared__ bf16_t wt[PM][LDK];   // [m][k]
  __shared__ bf16_t vt[DD][LDK];   // [d][k]
  __shared__ float Msh[PM], Ssh[PM];
  const int b = blockIdx.y;
  const int m0 = blockIdx.x * PM;
  const int tid = threadIdx.x;
  const int lane = tid & 63;
  const int wave = tid >> 6;      // 0..7
  const int wn = wave * 64;       // each wave owns a 64-wide d slice
  const int lrow = lane & 15;
  const int quad = lane >> 4;

  float* Lb = L + (size_t)b * SQ * SK;
  const float* Vb = V + (size_t)b * SK * DD;

  // ---- combine split-softmax partials: M = max_i m_i, S = sum s_i e^{m_i-M}
  if (tid < 4 * PM) {
    const int row = tid >> 2;       // 0..63
    const int i0 = (tid & 3) * 4;   // 4 partials per lane, 4 lanes per row
    float pm[4], ps[4];
#pragma unroll
    for (int j = 0; j < 4; j++) {
      const size_t o = ((size_t)b * NBLK + (i0 + j)) * SQ + (m0 + row);
      pm[j] = Mpart[o];
      ps[j] = Spart[o];
    }
    float m = fmaxf(fmaxf(pm[0], pm[1]), fmaxf(pm[2], pm[3]));
    m = fmaxf(m, __shfl_xor(m, 1));
    m = fmaxf(m, __shfl_xor(m, 2));
    float s = ps[0] * __expf(pm[0] - m) + ps[1] * __expf(pm[1] - m) +
              ps[2] * __expf(pm[2] - m) + ps[3] * __expf(pm[3] - m);
    s += __shfl_xor(s, 1);
    s += __shfl_xor(s, 2);
    if ((tid & 3) == 0) {
      Msh[row] = m;
      Ssh[row] = 1.0f / s;
    }
  }
  __syncthreads();

  const int srow = tid >> 3;        // 0..63: W staging row
  const int scol = (tid & 7) * 4;   // 0,4,...,28
  const int p = tid & 15;           // kpair: handles k = 2p, 2p+1
  const int c = tid >> 4;           // 0..31: d-chunks 4c + 128j, j=0..3

  float* wbase = Lb + (size_t)(m0 + srow) * SK + scol;
  const float* vbase = Vb + (size_t)(2 * p) * DD + 4 * c;
  const float Mv = Msh[srow];
  const float Sv = Ssh[srow];

  f32x4 acc[4][4];
#pragma unroll
  for (int i = 0; i < 4; i++)
#pragma unroll
    for (int j = 0; j < 4; j++) acc[i][j] = (f32x4){0.f, 0.f, 0.f, 0.f};

  float4 pw;
  float4 va[4], vb2[4];
  pw = *(const float4*)(wbase);
#pragma unroll
  for (int j = 0; j < 4; j++) {
    va[j] = *(const float4*)(vbase + 128 * j);
    vb2[j] = *(const float4*)(vbase + 128 * j + DD);
  }

  for (int k0 = 0; k0 < SK; k0 += BK) {
    __syncthreads();  // previous iteration's LDS reads complete
    // ---- normalize w = exp(s-M)/S, write weights back in place, stage bf16
    {
      float4 w = pw;
      const float w0 = __expf(w.x - Mv) * Sv;
      const float w1 = __expf(w.y - Mv) * Sv;
      const float w2 = __expf(w.z - Mv) * Sv;
      const float w3 = __expf(w.w - Mv) * Sv;
      float4 nw;
      nw.x = w0; nw.y = w1; nw.z = w2; nw.w = w3;
      *(float4*)(wbase + k0) = nw;   // weights output (this block owns rows)
      bf16x4 w4 = {(bf16_t)w0, (bf16_t)w1, (bf16_t)w2, (bf16_t)w3};
      *(bf16x4*)&wt[srow][scol] = w4;
    }
    // ---- V pair-pack transpose stage (2-way-bank, free)
#pragma unroll
    for (int j = 0; j < 4; j++) {
      const int d0 = 4 * c + 128 * j;
      float4 a0 = va[j], a1 = vb2[j];
      bf16x2 t0 = {(bf16_t)a0.x, (bf16_t)a1.x};
      bf16x2 t1 = {(bf16_t)a0.y, (bf16_t)a1.y};
      bf16x2 t2 = {(bf16_t)a0.z, (bf16_t)a1.z};
      bf16x2 t3 = {(bf16_t)a0.w, (bf16_t)a1.w};
      *(bf16x2*)&vt[d0 + 0][2 * p] = t0;
      *(bf16x2*)&vt[d0 + 1][2 * p] = t1;
      *(bf16x2*)&vt[d0 + 2][2 * p] = t2;
      *(bf16x2*)&vt[d0 + 3][2 * p] = t3;
    }
    __syncthreads();

    // ---- prefetch next tile (global reads only)
    if (k0 + BK < SK) {
      pw = *(const float4*)(wbase + k0 + BK);
      const float* vbk = vbase + (size_t)(k0 + BK) * DD;
#pragma unroll
      for (int j = 0; j < 4; j++) {
        va[j] = *(const float4*)(vbk + 128 * j);
        vb2[j] = *(const float4*)(vbk + 128 * j + DD);
      }
    }

    // ---- MFMA phase (wave: 64 rows x its 64-wide d slice)
    bf16x8 bb[4];
#pragma unroll
    for (int ni = 0; ni < 4; ni++)
      bb[ni] = *(const bf16x8*)&vt[wn + ni * 16 + lrow][quad * 8];
#pragma unroll
    for (int mi = 0; mi < 4; mi++) {
      bf16x8 a = *(const bf16x8*)&wt[mi * 16 + lrow][quad * 8];
#pragma unroll
      for (int ni = 0; ni < 4; ni++)
        acc[mi][ni] = __builtin_amdgcn_mfma_f32_16x16x32_bf16(a, bb[ni], acc[mi][ni], 0, 0, 0);
    }
  }

  float* Ob = O + (size_t)b * SQ * DD;
#pragma unroll
  for (int ni = 0; ni < 4; ni++) {
    const int d = wn + ni * 16 + lrow;
#pragma unroll
    for (int mi = 0; mi < 4; mi++) {
      const int mbase = m0 + mi * 16 + quad * 4;
#pragma unroll
      for (int r = 0; r < 4; r++) {
        Ob[(size_t)(mbase + r) * DD + d] = acc[mi][ni][r];
      }
    }
  }
}

extern "C" void kernel_launch(void* const* d_in, const int* in_sizes, int n_in,
                              void* d_out, int out_size, void* d_ws, size_t ws_size,
                              hipStream_t stream) {
  const float* Q = (const float*)d_in[0];
  const float* K = (const float*)d_in[1];
  const float* V = (const float*)d_in[2];
  const float* T = (const float*)d_in[3];

  float* outv = (float*)d_out;                          // [8,2048,512]
  float* logits = outv + (size_t)NB * SQ * DD;          // [8,2048,2048] weights region

  // softmax split-partials in workspace: 2 x [8][16][2048] f32 = 2 MB
  float* Mpart = (float*)d_ws;
  float* Spart = Mpart + (size_t)NB * NBLK * SQ;

  logits_kernel<<<dim3(SK / BN, SQ / BM, NB), 256, 0, stream>>>(Q, K, T, logits,
                                                                Mpart, Spart);
  pv_kernel<<<dim3(SQ / PM, NB), 512, 0, stream>>>(logits, V, Mpart, Spart, outv);
}

// Round 2
// 509.022 us; speedup vs baseline: 1.0451x; 1.0451x over previous
//
#include <hip/hip_runtime.h>

typedef __bf16 bf16_t;
typedef __bf16 bf16x8 __attribute__((ext_vector_type(8)));
typedef __bf16 bf16x4 __attribute__((ext_vector_type(4)));
typedef __bf16 bf16x2 __attribute__((ext_vector_type(2)));
typedef float f32x4 __attribute__((ext_vector_type(4)));

#define NB 8
#define SQ 2048
#define SK 2048
#define DD 512

#define BM 128
#define BN 128
#define BK 32
#define LDK 40   // padded LDS row stride (80 B, 16B-aligned rows for b128)
#define NBLK (SK / BN)   // n-blocks per row = softmax partial count

// ------------------------------------------------- logits = (2 q.k - k^2)/T
// (unchanged from previous round) bf16 hi/lo split GEMM, fp32 accum.
// Epilogue emits per-(row, n-block) softmax partials (m_i, s_i).
__global__ __launch_bounds__(256, 2) void logits_kernel(
    const float* __restrict__ Q, const float* __restrict__ K,
    const float* __restrict__ tempP, float* __restrict__ logits,
    float* __restrict__ Mpart, float* __restrict__ Spart) {
  __shared__ bf16_t qh[BM][LDK], ql[BM][LDK], kh[BN][LDK], kl[BN][LDK];
  __shared__ float ksred[BN][8];
  __shared__ float mred[BM][2], sred[BM][2];
  const int b = blockIdx.z;
  const int m0 = blockIdx.y * BM;
  const int n0 = blockIdx.x * BN;
  const int tid = threadIdx.x;
  const int lane = tid & 63;
  const int wave = tid >> 6;
  const int wm = (wave >> 1) * 64;
  const int wn = (wave & 1) * 64;
  const int lrow = lane & 15;
  const int quad = lane >> 4;

  const float* Qb = Q + (size_t)b * SQ * DD;
  const float* Kb = K + (size_t)b * SK * DD;

  const int srow = tid >> 3;        // 0..31
  const int scol = (tid & 7) * 4;   // 0,4,...,28

  const float* qbase = Qb + (size_t)(m0 + srow) * DD + scol;
  const float* kbase = Kb + (size_t)(n0 + srow) * DD + scol;

  f32x4 acc[4][4];
#pragma unroll
  for (int i = 0; i < 4; i++)
#pragma unroll
    for (int j = 0; j < 4; j++) acc[i][j] = (f32x4){0.f, 0.f, 0.f, 0.f};

  float kss[4] = {0.f, 0.f, 0.f, 0.f};

  float4 pq[4], pk[4];
#pragma unroll
  for (int i = 0; i < 4; i++) {
    pq[i] = *(const float4*)(qbase + (size_t)i * 32 * DD);
    pk[i] = *(const float4*)(kbase + (size_t)i * 32 * DD);
  }

  for (int k0 = 0; k0 < DD; k0 += BK) {
    __syncthreads();
#pragma unroll
    for (int i = 0; i < 4; i++) {
      const int r = srow + i * 32;
      float4 qv = pq[i], kv = pk[i];
      bf16_t q0 = (bf16_t)qv.x, q1 = (bf16_t)qv.y, q2 = (bf16_t)qv.z, q3 = (bf16_t)qv.w;
      bf16x4 qhv = {q0, q1, q2, q3};
      bf16x4 qlv = {(bf16_t)(qv.x - (float)q0), (bf16_t)(qv.y - (float)q1),
                    (bf16_t)(qv.z - (float)q2), (bf16_t)(qv.w - (float)q3)};
      bf16_t c0 = (bf16_t)kv.x, c1 = (bf16_t)kv.y, c2 = (bf16_t)kv.z, c3 = (bf16_t)kv.w;
      bf16x4 khv = {c0, c1, c2, c3};
      bf16x4 klv = {(bf16_t)(kv.x - (float)c0), (bf16_t)(kv.y - (float)c1),
                    (bf16_t)(kv.z - (float)c2), (bf16_t)(kv.w - (float)c3)};
      *(bf16x4*)&qh[r][scol] = qhv;
      *(bf16x4*)&ql[r][scol] = qlv;
      *(bf16x4*)&kh[r][scol] = khv;
      *(bf16x4*)&kl[r][scol] = klv;
      kss[i] = fmaf(kv.x, kv.x, kss[i]);
      kss[i] = fmaf(kv.y, kv.y, kss[i]);
      kss[i] = fmaf(kv.z, kv.z, kss[i]);
      kss[i] = fmaf(kv.w, kv.w, kss[i]);
    }
    __syncthreads();

    if (k0 + BK < DD) {
#pragma unroll
      for (int i = 0; i < 4; i++) {
        pq[i] = *(const float4*)(qbase + (size_t)i * 32 * DD + (k0 + BK));
        pk[i] = *(const float4*)(kbase + (size_t)i * 32 * DD + (k0 + BK));
      }
    }

    bf16x8 bh[4], bl[4];
#pragma unroll
    for (int ni = 0; ni < 4; ni++) {
      bh[ni] = *(const bf16x8*)&kh[wn + ni * 16 + lrow][quad * 8];
      bl[ni] = *(const bf16x8*)&kl[wn + ni * 16 + lrow][quad * 8];
    }
#pragma unroll
    for (int mi = 0; mi < 4; mi++) {
      bf16x8 ah = *(const bf16x8*)&qh[wm + mi * 16 + lrow][quad * 8];
      bf16x8 al = *(const bf16x8*)&ql[wm + mi * 16 + lrow][quad * 8];
#pragma unroll
      for (int ni = 0; ni < 4; ni++) {
        acc[mi][ni] = __builtin_amdgcn_mfma_f32_16x16x32_bf16(ah, bh[ni], acc[mi][ni], 0, 0, 0);
        acc[mi][ni] = __builtin_amdgcn_mfma_f32_16x16x32_bf16(ah, bl[ni], acc[mi][ni], 0, 0, 0);
        acc[mi][ni] = __builtin_amdgcn_mfma_f32_16x16x32_bf16(al, bh[ni], acc[mi][ni], 0, 0, 0);
      }
    }
  }

#pragma unroll
  for (int i = 0; i < 4; i++) ksred[srow + i * 32][tid & 7] = kss[i];
  __syncthreads();

  const float invT = 1.0f / tempP[0];
  float* Lb = logits + (size_t)b * SQ * SK;
  float ks4[4];
#pragma unroll
  for (int ni = 0; ni < 4; ni++) {
    const float* kr = ksred[wn + ni * 16 + lrow];
    ks4[ni] = ((kr[0] + kr[1]) + (kr[2] + kr[3])) +
              ((kr[4] + kr[5]) + (kr[6] + kr[7]));
  }

#pragma unroll
  for (int mi = 0; mi < 4; mi++) {
#pragma unroll
    for (int r = 0; r < 4; r++) {
      const int row = wm + mi * 16 + quad * 4 + r;
      float sv[4];
#pragma unroll
      for (int ni = 0; ni < 4; ni++) {
        sv[ni] = (2.0f * acc[mi][ni][r] - ks4[ni]) * invT;
        Lb[(size_t)(m0 + row) * SK + (n0 + wn + ni * 16 + lrow)] = sv[ni];
      }
      float rm = fmaxf(fmaxf(sv[0], sv[1]), fmaxf(sv[2], sv[3]));
      rm = fmaxf(rm, __shfl_xor(rm, 1));
      rm = fmaxf(rm, __shfl_xor(rm, 2));
      rm = fmaxf(rm, __shfl_xor(rm, 4));
      rm = fmaxf(rm, __shfl_xor(rm, 8));
      float rs = __expf(sv[0] - rm) + __expf(sv[1] - rm) +
                 __expf(sv[2] - rm) + __expf(sv[3] - rm);
      rs += __shfl_xor(rs, 1);
      rs += __shfl_xor(rs, 2);
      rs += __shfl_xor(rs, 4);
      rs += __shfl_xor(rs, 8);
      if (lrow == 0) {
        mred[row][wave & 1] = rm;
        sred[row][wave & 1] = rs;
      }
    }
  }
  __syncthreads();
  if (tid < BM) {
    const float ma = mred[tid][0], mb = mred[tid][1];
    const float M = fmaxf(ma, mb);
    const float S = sred[tid][0] * __expf(ma - M) + sred[tid][1] * __expf(mb - M);
    const size_t o = ((size_t)b * NBLK + blockIdx.x) * SQ + (m0 + tid);
    Mpart[o] = M;
    Spart[o] = S;
  }
}

// ------------------------------------------------- Vt[b][d][k] bf16 = V^T
// Pair-pack transpose: thread (p,c) packs (V[2p][d],V[2p+1][d]) into one
// 4B store; per instruction 16 lanes cover 64 contiguous bytes of a d-row.
__global__ __launch_bounds__(256) void vt_kernel(const float* __restrict__ V,
                                                 bf16_t* __restrict__ Vt) {
  const int b = blockIdx.y;
  const int k0 = blockIdx.x * 32;
  const int tid = threadIdx.x;
  const int p = tid & 15;
  const int c = tid >> 4;
  const float* Vb = V + (size_t)b * SK * DD;
  bf16_t* Vtb = Vt + (size_t)b * DD * SK;
  const int k = k0 + 2 * p;
#pragma unroll
  for (int j = 0; j < 8; j++) {
    const int d0 = 4 * c + 64 * j;
    float4 v0 = *(const float4*)(Vb + (size_t)k * DD + d0);
    float4 v1 = *(const float4*)(Vb + (size_t)(k + 1) * DD + d0);
    bf16x2 t0 = {(bf16_t)v0.x, (bf16_t)v1.x};
    bf16x2 t1 = {(bf16_t)v0.y, (bf16_t)v1.y};
    bf16x2 t2 = {(bf16_t)v0.z, (bf16_t)v1.z};
    bf16x2 t3 = {(bf16_t)v0.w, (bf16_t)v1.w};
    *(bf16x2*)(Vtb + (size_t)(d0 + 0) * SK + k) = t0;
    *(bf16x2*)(Vtb + (size_t)(d0 + 1) * SK + k) = t1;
    *(bf16x2*)(Vtb + (size_t)(d0 + 2) * SK + k) = t2;
    *(bf16x2*)(Vtb + (size_t)(d0 + 3) * SK + k) = t3;
  }
}

// ------------------------------------------------- fused softmax + O = W @ V
// LDS-free streaming PV. MFMA A-frag (8 consecutive k, fixed row) is
// contiguous in L[m][k]; B-frag is contiguous in Vt[d][k]. Each of 8 waves
// owns a 64-wide d slice of a 64-row tile, loads fragments straight from
// global (W from HBM/L2, Vt 2MB/batch L2-resident), normalizes in-register.
// Raw s_barrier (no vmcnt drain -> prefetches stay in flight) orders the
// in-place normalized-W write (wave 0) after all waves consumed the window.
// Batch pinned to XCD (bid&7) so each XCD L2 caches one Vt.
#define PM 64

__global__ __launch_bounds__(512, 2) void pv_kernel(
    float* __restrict__ L,               // raw logits in, weights out (in place)
    const bf16_t* __restrict__ Vt,
    const float* __restrict__ Mpart, const float* __restrict__ Spart,
    float* __restrict__ O) {
  __shared__ float Msh[PM], Ssh[PM];
  const int bid = blockIdx.x;
  const int b = bid & 7;            // XCD affinity
  const int m0 = (bid >> 3) * PM;
  const int tid = threadIdx.x;
  const int lane = tid & 63;
  const int wave = tid >> 6;        // 0..7
  const int wn = wave * 64;         // wave's d slice
  const int lrow = lane & 15;
  const int quad = lane >> 4;

  float* Lb = L + (size_t)b * SQ * SK;
  const bf16_t* Vtb = Vt + (size_t)b * DD * SK;

  // ---- combine split-softmax partials
  if (tid < 4 * PM) {
    const int row = tid >> 2;
    const int i0 = (tid & 3) * 4;
    float pm[4], ps[4];
#pragma unroll
    for (int j = 0; j < 4; j++) {
      const size_t o = ((size_t)b * NBLK + (i0 + j)) * SQ + (m0 + row);
      pm[j] = Mpart[o];
      ps[j] = Spart[o];
    }
    float m = fmaxf(fmaxf(pm[0], pm[1]), fmaxf(pm[2], pm[3]));
    m = fmaxf(m, __shfl_xor(m, 1));
    m = fmaxf(m, __shfl_xor(m, 2));
    float s = ps[0] * __expf(pm[0] - m) + ps[1] * __expf(pm[1] - m) +
              ps[2] * __expf(pm[2] - m) + ps[3] * __expf(pm[3] - m);
    s += __shfl_xor(s, 1);
    s += __shfl_xor(s, 2);
    if ((tid & 3) == 0) {
      Msh[row] = m;
      Ssh[row] = 1.0f / s;
    }
  }
  __syncthreads();

  float Mv[4], Sv[4];
  float* Arow[4];
  const bf16_t* Brow[4];
#pragma unroll
  for (int i = 0; i < 4; i++) {
    const int r = i * 16 + lrow;
    Mv[i] = Msh[r];
    Sv[i] = Ssh[r];
    Arow[i] = Lb + (size_t)(m0 + r) * SK + quad * 8;
    Brow[i] = Vtb + (size_t)(wn + r) * SK + quad * 8;
  }

  f32x4 acc[4][4];
#pragma unroll
  for (int i = 0; i < 4; i++)
#pragma unroll
    for (int j = 0; j < 4; j++) acc[i][j] = (f32x4){0.f, 0.f, 0.f, 0.f};

  float4 rawA[4][2], rawB[4][2];
  bf16x8 bb[4];

  // prologue: A windows 0 and BK; B window 0
#pragma unroll
  for (int mi = 0; mi < 4; mi++) {
    rawA[mi][0] = *(const float4*)(Arow[mi]);
    rawA[mi][1] = *(const float4*)(Arow[mi] + 4);
    rawB[mi][0] = *(const float4*)(Arow[mi] + BK);
    rawB[mi][1] = *(const float4*)(Arow[mi] + BK + 4);
  }
#pragma unroll
  for (int ni = 0; ni < 4; ni++) bb[ni] = *(const bf16x8*)(Brow[ni]);

  auto process = [&](float4 (&buf)[4][2], const int kw) {
    float4 nw[4][2];
    bf16x8 af[4];
#pragma unroll
    for (int mi = 0; mi < 4; mi++) {
      float4 r0 = buf[mi][0], r1 = buf[mi][1];
      float e0 = __expf(r0.x - Mv[mi]) * Sv[mi];
      float e1 = __expf(r0.y - Mv[mi]) * Sv[mi];
      float e2 = __expf(r0.z - Mv[mi]) * Sv[mi];
      float e3 = __expf(r0.w - Mv[mi]) * Sv[mi];
      float e4 = __expf(r1.x - Mv[mi]) * Sv[mi];
      float e5 = __expf(r1.y - Mv[mi]) * Sv[mi];
      float e6 = __expf(r1.z - Mv[mi]) * Sv[mi];
      float e7 = __expf(r1.w - Mv[mi]) * Sv[mi];
      nw[mi][0] = make_float4(e0, e1, e2, e3);
      nw[mi][1] = make_float4(e4, e5, e6, e7);
      af[mi] = (bf16x8){(bf16_t)e0, (bf16_t)e1, (bf16_t)e2, (bf16_t)e3,
                        (bf16_t)e4, (bf16_t)e5, (bf16_t)e6, (bf16_t)e7};
    }
    // prefetch A two windows ahead into the just-consumed buffer
    if (kw + 2 * BK < SK) {
#pragma unroll
      for (int mi = 0; mi < 4; mi++) {
        buf[mi][0] = *(const float4*)(Arow[mi] + kw + 2 * BK);
        buf[mi][1] = *(const float4*)(Arow[mi] + kw + 2 * BK + 4);
      }
    }
#pragma unroll
    for (int mi = 0; mi < 4; mi++)
#pragma unroll
      for (int ni = 0; ni < 4; ni++)
        acc[mi][ni] = __builtin_amdgcn_mfma_f32_16x16x32_bf16(af[mi], bb[ni],
                                                              acc[mi][ni], 0, 0, 0);
    // next-window B (L2-resident Vt)
    if (kw + BK < SK) {
#pragma unroll
      for (int ni = 0; ni < 4; ni++)
        bb[ni] = *(const bf16x8*)(Brow[ni] + kw + BK);
    }
    // raw barrier: all waves consumed raw window kw (reads completed before
    // their MFMA); prefetches of kw+BK/kw+2BK stay in flight across it.
    asm volatile("s_barrier" ::: "memory");
    if (wave == 0) {
#pragma unroll
      for (int mi = 0; mi < 4; mi++) {
        *(float4*)(Arow[mi] + kw) = nw[mi][0];
        *(float4*)(Arow[mi] + kw + 4) = nw[mi][1];
      }
    }
  };

  for (int k0 = 0; k0 < SK; k0 += 2 * BK) {
    process(rawA, k0);
    process(rawB, k0 + BK);
  }

  float* Ob = O + (size_t)b * SQ * DD;
#pragma unroll
  for (int ni = 0; ni < 4; ni++) {
    const int d = wn + ni * 16 + lrow;
#pragma unroll
    for (int mi = 0; mi < 4; mi++) {
      const int mbase = m0 + mi * 16 + quad * 4;
#pragma unroll
      for (int r = 0; r < 4; r++) {
        Ob[(size_t)(mbase + r) * DD + d] = acc[mi][ni][r];
      }
    }
  }
}

extern "C" void kernel_launch(void* const* d_in, const int* in_sizes, int n_in,
                              void* d_out, int out_size, void* d_ws, size_t ws_size,
                              hipStream_t stream) {
  const float* Q = (const float*)d_in[0];
  const float* K = (const float*)d_in[1];
  const float* V = (const float*)d_in[2];
  const float* T = (const float*)d_in[3];

  float* outv = (float*)d_out;                          // [8,2048,512]
  float* logits = outv + (size_t)NB * SQ * DD;          // [8,2048,2048] weights region

  // workspace: softmax partials (2 MB) + Vt bf16 (16.8 MB)
  float* Mpart = (float*)d_ws;
  float* Spart = Mpart + (size_t)NB * NBLK * SQ;
  bf16_t* Vt = (bf16_t*)(Spart + (size_t)NB * NBLK * SQ);

  vt_kernel<<<dim3(SK / 32, NB), 256, 0, stream>>>(V, Vt);
  logits_kernel<<<dim3(SK / BN, SQ / BM, NB), 256, 0, stream>>>(Q, K, T, logits,
                                                                Mpart, Spart);
  pv_kernel<<<dim3(NB * (SQ / PM)), 512, 0, stream>>>(logits, Vt, Mpart, Spart, outv);
}

// Round 3
// 474.479 us; speedup vs baseline: 1.1212x; 1.0728x over previous
//
#include <hip/hip_runtime.h>

typedef __bf16 bf16_t;
typedef __bf16 bf16x8 __attribute__((ext_vector_type(8)));
typedef __bf16 bf16x4 __attribute__((ext_vector_type(4)));
typedef __bf16 bf16x2 __attribute__((ext_vector_type(2)));
typedef float f32x4 __attribute__((ext_vector_type(4)));

#define NB 8
#define SQ 2048
#define SK 2048
#define DD 512

#define BM 128
#define BN 128
#define BK 32
#define LDK 40   // padded LDS row stride (80 B, 16B-aligned rows for b128)
#define NBLK (SK / BN)   // n-blocks per row = softmax partial count

// ------------------------------------------------- logits = (2 q.k - k^2)/T
// (unchanged) bf16 hi/lo split GEMM, fp32 accum. Epilogue emits per-(row,
// n-block) softmax partials (m_i, s_i).
__global__ __launch_bounds__(256, 2) void logits_kernel(
    const float* __restrict__ Q, const float* __restrict__ K,
    const float* __restrict__ tempP, float* __restrict__ logits,
    float* __restrict__ Mpart, float* __restrict__ Spart) {
  __shared__ bf16_t qh[BM][LDK], ql[BM][LDK], kh[BN][LDK], kl[BN][LDK];
  __shared__ float ksred[BN][8];
  __shared__ float mred[BM][2], sred[BM][2];
  const int b = blockIdx.z;
  const int m0 = blockIdx.y * BM;
  const int n0 = blockIdx.x * BN;
  const int tid = threadIdx.x;
  const int lane = tid & 63;
  const int wave = tid >> 6;
  const int wm = (wave >> 1) * 64;
  const int wn = (wave & 1) * 64;
  const int lrow = lane & 15;
  const int quad = lane >> 4;

  const float* Qb = Q + (size_t)b * SQ * DD;
  const float* Kb = K + (size_t)b * SK * DD;

  const int srow = tid >> 3;        // 0..31
  const int scol = (tid & 7) * 4;   // 0,4,...,28

  const float* qbase = Qb + (size_t)(m0 + srow) * DD + scol;
  const float* kbase = Kb + (size_t)(n0 + srow) * DD + scol;

  f32x4 acc[4][4];
#pragma unroll
  for (int i = 0; i < 4; i++)
#pragma unroll
    for (int j = 0; j < 4; j++) acc[i][j] = (f32x4){0.f, 0.f, 0.f, 0.f};

  float kss[4] = {0.f, 0.f, 0.f, 0.f};

  float4 pq[4], pk[4];
#pragma unroll
  for (int i = 0; i < 4; i++) {
    pq[i] = *(const float4*)(qbase + (size_t)i * 32 * DD);
    pk[i] = *(const float4*)(kbase + (size_t)i * 32 * DD);
  }

  for (int k0 = 0; k0 < DD; k0 += BK) {
    __syncthreads();
#pragma unroll
    for (int i = 0; i < 4; i++) {
      const int r = srow + i * 32;
      float4 qv = pq[i], kv = pk[i];
      bf16_t q0 = (bf16_t)qv.x, q1 = (bf16_t)qv.y, q2 = (bf16_t)qv.z, q3 = (bf16_t)qv.w;
      bf16x4 qhv = {q0, q1, q2, q3};
      bf16x4 qlv = {(bf16_t)(qv.x - (float)q0), (bf16_t)(qv.y - (float)q1),
                    (bf16_t)(qv.z - (float)q2), (bf16_t)(qv.w - (float)q3)};
      bf16_t c0 = (bf16_t)kv.x, c1 = (bf16_t)kv.y, c2 = (bf16_t)kv.z, c3 = (bf16_t)kv.w;
      bf16x4 khv = {c0, c1, c2, c3};
      bf16x4 klv = {(bf16_t)(kv.x - (float)c0), (bf16_t)(kv.y - (float)c1),
                    (bf16_t)(kv.z - (float)c2), (bf16_t)(kv.w - (float)c3)};
      *(bf16x4*)&qh[r][scol] = qhv;
      *(bf16x4*)&ql[r][scol] = qlv;
      *(bf16x4*)&kh[r][scol] = khv;
      *(bf16x4*)&kl[r][scol] = klv;
      kss[i] = fmaf(kv.x, kv.x, kss[i]);
      kss[i] = fmaf(kv.y, kv.y, kss[i]);
      kss[i] = fmaf(kv.z, kv.z, kss[i]);
      kss[i] = fmaf(kv.w, kv.w, kss[i]);
    }
    __syncthreads();

    if (k0 + BK < DD) {
#pragma unroll
      for (int i = 0; i < 4; i++) {
        pq[i] = *(const float4*)(qbase + (size_t)i * 32 * DD + (k0 + BK));
        pk[i] = *(const float4*)(kbase + (size_t)i * 32 * DD + (k0 + BK));
      }
    }

    bf16x8 bh[4], bl[4];
#pragma unroll
    for (int ni = 0; ni < 4; ni++) {
      bh[ni] = *(const bf16x8*)&kh[wn + ni * 16 + lrow][quad * 8];
      bl[ni] = *(const bf16x8*)&kl[wn + ni * 16 + lrow][quad * 8];
    }
#pragma unroll
    for (int mi = 0; mi < 4; mi++) {
      bf16x8 ah = *(const bf16x8*)&qh[wm + mi * 16 + lrow][quad * 8];
      bf16x8 al = *(const bf16x8*)&ql[wm + mi * 16 + lrow][quad * 8];
#pragma unroll
      for (int ni = 0; ni < 4; ni++) {
        acc[mi][ni] = __builtin_amdgcn_mfma_f32_16x16x32_bf16(ah, bh[ni], acc[mi][ni], 0, 0, 0);
        acc[mi][ni] = __builtin_amdgcn_mfma_f32_16x16x32_bf16(ah, bl[ni], acc[mi][ni], 0, 0, 0);
        acc[mi][ni] = __builtin_amdgcn_mfma_f32_16x16x32_bf16(al, bh[ni], acc[mi][ni], 0, 0, 0);
      }
    }
  }

#pragma unroll
  for (int i = 0; i < 4; i++) ksred[srow + i * 32][tid & 7] = kss[i];
  __syncthreads();

  const float invT = 1.0f / tempP[0];
  float* Lb = logits + (size_t)b * SQ * SK;
  float ks4[4];
#pragma unroll
  for (int ni = 0; ni < 4; ni++) {
    const float* kr = ksred[wn + ni * 16 + lrow];
    ks4[ni] = ((kr[0] + kr[1]) + (kr[2] + kr[3])) +
              ((kr[4] + kr[5]) + (kr[6] + kr[7]));
  }

#pragma unroll
  for (int mi = 0; mi < 4; mi++) {
#pragma unroll
    for (int r = 0; r < 4; r++) {
      const int row = wm + mi * 16 + quad * 4 + r;
      float sv[4];
#pragma unroll
      for (int ni = 0; ni < 4; ni++) {
        sv[ni] = (2.0f * acc[mi][ni][r] - ks4[ni]) * invT;
        Lb[(size_t)(m0 + row) * SK + (n0 + wn + ni * 16 + lrow)] = sv[ni];
      }
      float rm = fmaxf(fmaxf(sv[0], sv[1]), fmaxf(sv[2], sv[3]));
      rm = fmaxf(rm, __shfl_xor(rm, 1));
      rm = fmaxf(rm, __shfl_xor(rm, 2));
      rm = fmaxf(rm, __shfl_xor(rm, 4));
      rm = fmaxf(rm, __shfl_xor(rm, 8));
      float rs = __expf(sv[0] - rm) + __expf(sv[1] - rm) +
                 __expf(sv[2] - rm) + __expf(sv[3] - rm);
      rs += __shfl_xor(rs, 1);
      rs += __shfl_xor(rs, 2);
      rs += __shfl_xor(rs, 4);
      rs += __shfl_xor(rs, 8);
      if (lrow == 0) {
        mred[row][wave & 1] = rm;
        sred[row][wave & 1] = rs;
      }
    }
  }
  __syncthreads();
  if (tid < BM) {
    const float ma = mred[tid][0], mb = mred[tid][1];
    const float M = fmaxf(ma, mb);
    const float S = sred[tid][0] * __expf(ma - M) + sred[tid][1] * __expf(mb - M);
    const size_t o = ((size_t)b * NBLK + blockIdx.x) * SQ + (m0 + tid);
    Mpart[o] = M;
    Spart[o] = S;
  }
}

// ------------------------------------------------- Vt[b][d][k] bf16 = V^T
__global__ __launch_bounds__(256) void vt_kernel(const float* __restrict__ V,
                                                 bf16_t* __restrict__ Vt) {
  const int b = blockIdx.y;
  const int k0 = blockIdx.x * 32;
  const int tid = threadIdx.x;
  const int p = tid & 15;
  const int c = tid >> 4;
  const float* Vb = V + (size_t)b * SK * DD;
  bf16_t* Vtb = Vt + (size_t)b * DD * SK;
  const int k = k0 + 2 * p;
#pragma unroll
  for (int j = 0; j < 8; j++) {
    const int d0 = 4 * c + 64 * j;
    float4 v0 = *(const float4*)(Vb + (size_t)k * DD + d0);
    float4 v1 = *(const float4*)(Vb + (size_t)(k + 1) * DD + d0);
    bf16x2 t0 = {(bf16_t)v0.x, (bf16_t)v1.x};
    bf16x2 t1 = {(bf16_t)v0.y, (bf16_t)v1.y};
    bf16x2 t2 = {(bf16_t)v0.z, (bf16_t)v1.z};
    bf16x2 t3 = {(bf16_t)v0.w, (bf16_t)v1.w};
    *(bf16x2*)(Vtb + (size_t)(d0 + 0) * SK + k) = t0;
    *(bf16x2*)(Vtb + (size_t)(d0 + 1) * SK + k) = t1;
    *(bf16x2*)(Vtb + (size_t)(d0 + 2) * SK + k) = t2;
    *(bf16x2*)(Vtb + (size_t)(d0 + 3) * SK + k) = t3;
  }
}

// ------------------------------------------------- fused softmax + O = W @ V
// Two-phase, LDS-panel design. Block = 32 query rows x ALL d (single owner
// of its W rows -> in-place normalized-W write is race-free).
// Phase 1: combine split-softmax partials; stream raw L once: write
//   normalized W in place (global) AND deposit bf16 W into a 128 KB
//   XOR-swizzled LDS panel [32][2048].
// Phase 2: GEMM with ZERO barriers: A-frags from read-only LDS (conflict-
//   free b128 via swizzle), B-frags stream from L2-resident Vt (wave-private
//   d-slice, double-buffered 2 windows deep). No redundant work across waves.
// Batch pinned to XCD (bid&7) so each XCD's L2 holds one 2 MB Vt.
#define PM 32

__device__ __forceinline__ unsigned lds_addr(int row, unsigned kb) {
  return (unsigned)row * 4096u + (kb ^ (unsigned)((row & 7) << 4));
}

__global__ __launch_bounds__(512, 1) void pv_kernel(
    float* __restrict__ L,               // raw logits in, weights out (in place)
    const bf16_t* __restrict__ Vt,
    const float* __restrict__ Mpart, const float* __restrict__ Spart,
    float* __restrict__ O) {
  __shared__ __align__(16) unsigned char wlds[PM * 4096];  // [32][2048] bf16 swz
  __shared__ float Msh[PM], Ssh[PM];
  const int bid = blockIdx.x;
  const int b = bid & 7;            // XCD affinity: batch b -> XCD b
  const int m0 = (bid >> 3) * PM;
  const int tid = threadIdx.x;

  float* Lb = L + (size_t)b * SQ * SK;
  const bf16_t* Vtb = Vt + (size_t)b * DD * SK;

  // ---- combine split-softmax partials: 16 threads per row, 1 partial each
  {
    const int row = tid >> 4;       // 0..31
    const int j = tid & 15;         // partial index
    const size_t o = ((size_t)b * NBLK + j) * SQ + (m0 + row);
    const float pm = Mpart[o];
    const float ps = Spart[o];
    float m = pm;
    m = fmaxf(m, __shfl_xor(m, 1));
    m = fmaxf(m, __shfl_xor(m, 2));
    m = fmaxf(m, __shfl_xor(m, 4));
    m = fmaxf(m, __shfl_xor(m, 8));
    float s = ps * __expf(pm - m);
    s += __shfl_xor(s, 1);
    s += __shfl_xor(s, 2);
    s += __shfl_xor(s, 4);
    s += __shfl_xor(s, 8);
    if (j == 0) {
      Msh[row] = m;
      Ssh[row] = 1.0f / s;
    }
  }
  __syncthreads();

  // ---- phase 1: normalize panel in place + build LDS bf16 panel
  {
    const int row = tid >> 4;       // 0..31
    const int g = tid & 15;         // 16 threads span a row
    float* lp = Lb + (size_t)(m0 + row) * SK;
    const float M = Msh[row];
    const float invS = Ssh[row];
#pragma unroll 8
    for (int j = 0; j < 32; j++) {
      const int k = g * 4 + j * 64;   // 16-lane groups load 256 B contiguous
      float4 v = *(const float4*)(lp + k);
      const float w0 = __expf(v.x - M) * invS;
      const float w1 = __expf(v.y - M) * invS;
      const float w2 = __expf(v.z - M) * invS;
      const float w3 = __expf(v.w - M) * invS;
      *(float4*)(lp + k) = make_float4(w0, w1, w2, w3);  // weights output
      bf16x4 w4 = {(bf16_t)w0, (bf16_t)w1, (bf16_t)w2, (bf16_t)w3};
      *(bf16x4*)(wlds + lds_addr(row, (unsigned)(k * 2))) = w4;
    }
  }
  __syncthreads();

  // ---- phase 2: barrier-free GEMM. wave -> 64-wide d slice; A from LDS.
  const int lane = tid & 63;
  const int wave = tid >> 6;        // 0..7
  const int wn = wave * 64;
  const int lrow = lane & 15;
  const int quad = lane >> 4;

  const bf16_t* Brow[4];
#pragma unroll
  for (int ni = 0; ni < 4; ni++)
    Brow[ni] = Vtb + (size_t)(wn + ni * 16 + lrow) * SK + quad * 8;

  f32x4 acc[2][4];
#pragma unroll
  for (int i = 0; i < 2; i++)
#pragma unroll
    for (int j = 0; j < 4; j++) acc[i][j] = (f32x4){0.f, 0.f, 0.f, 0.f};

  bf16x8 b0[4], b1[4];
#pragma unroll
  for (int ni = 0; ni < 4; ni++) b0[ni] = *(const bf16x8*)(Brow[ni]);
#pragma unroll
  for (int ni = 0; ni < 4; ni++) b1[ni] = *(const bf16x8*)(Brow[ni] + BK);

  for (int k0 = 0; k0 < SK; k0 += 2 * BK) {
    bf16x8 a0[2], a1[2];
#pragma unroll
    for (int mi = 0; mi < 2; mi++) {
      const int row = mi * 16 + lrow;
      a0[mi] = *(const bf16x8*)(wlds + lds_addr(row, (unsigned)((k0 + quad * 8) * 2)));
      a1[mi] = *(const bf16x8*)(wlds + lds_addr(row, (unsigned)((k0 + BK + quad * 8) * 2)));
    }
#pragma unroll
    for (int mi = 0; mi < 2; mi++)
#pragma unroll
      for (int ni = 0; ni < 4; ni++)
        acc[mi][ni] = __builtin_amdgcn_mfma_f32_16x16x32_bf16(a0[mi], b0[ni],
                                                              acc[mi][ni], 0, 0, 0);
    if (k0 + 2 * BK < SK) {
#pragma unroll
      for (int ni = 0; ni < 4; ni++)
        b0[ni] = *(const bf16x8*)(Brow[ni] + k0 + 2 * BK);
    }
#pragma unroll
    for (int mi = 0; mi < 2; mi++)
#pragma unroll
      for (int ni = 0; ni < 4; ni++)
        acc[mi][ni] = __builtin_amdgcn_mfma_f32_16x16x32_bf16(a1[mi], b1[ni],
                                                              acc[mi][ni], 0, 0, 0);
    if (k0 + 3 * BK < SK) {
#pragma unroll
      for (int ni = 0; ni < 4; ni++)
        b1[ni] = *(const bf16x8*)(Brow[ni] + k0 + 3 * BK);
    }
  }

  float* Ob = O + (size_t)b * SQ * DD;
#pragma unroll
  for (int ni = 0; ni < 4; ni++) {
    const int d = wn + ni * 16 + lrow;
#pragma unroll
    for (int mi = 0; mi < 2; mi++) {
      const int mbase = m0 + mi * 16 + quad * 4;
#pragma unroll
      for (int r = 0; r < 4; r++) {
        Ob[(size_t)(mbase + r) * DD + d] = acc[mi][ni][r];
      }
    }
  }
}

extern "C" void kernel_launch(void* const* d_in, const int* in_sizes, int n_in,
                              void* d_out, int out_size, void* d_ws, size_t ws_size,
                              hipStream_t stream) {
  const float* Q = (const float*)d_in[0];
  const float* K = (const float*)d_in[1];
  const float* V = (const float*)d_in[2];
  const float* T = (const float*)d_in[3];

  float* outv = (float*)d_out;                          // [8,2048,512]
  float* logits = outv + (size_t)NB * SQ * DD;          // [8,2048,2048] weights region

  // workspace: softmax partials (2 MB) + Vt bf16 (16.8 MB)
  float* Mpart = (float*)d_ws;
  float* Spart = Mpart + (size_t)NB * NBLK * SQ;
  bf16_t* Vt = (bf16_t*)(Spart + (size_t)NB * NBLK * SQ);

  vt_kernel<<<dim3(SK / 32, NB), 256, 0, stream>>>(V, Vt);
  logits_kernel<<<dim3(SK / BN, SQ / BM, NB), 256, 0, stream>>>(Q, K, T, logits,
                                                                Mpart, Spart);
  pv_kernel<<<dim3(NB * (SQ / PM)), 512, 0, stream>>>(logits, Vt, Mpart, Spart, outv);
}

// Round 4
// 459.968 us; speedup vs baseline: 1.1566x; 1.0315x over previous
//
#include <hip/hip_runtime.h>

typedef __bf16 bf16_t;
typedef __bf16 bf16x8 __attribute__((ext_vector_type(8)));
typedef __bf16 bf16x4 __attribute__((ext_vector_type(4)));
typedef __bf16 bf16x2 __attribute__((ext_vector_type(2)));
typedef float f32x4 __attribute__((ext_vector_type(4)));

#define NB 8
#define SQ 2048
#define SK 2048
#define DD 512

#define BM 128
#define BN 128
#define BK 32
#define LDK 40   // padded LDS row stride (80 B, 16B-aligned rows for b128)
#define NBLK (SK / BN)   // n-blocks per row = softmax partial count

// ------------------------------------------------- logits = (2 q.k - k^2) * log2e/T
// bf16 hi/lo split GEMM, fp32 accum. BASE-2 domain: stored logits are
// pre-scaled by log2e so all downstream exps are single v_exp_f32 (exp2).
// Epilogue emits per-(row, n-block) base-2 softmax partials (m_i, s_i).
__global__ __launch_bounds__(256, 2) void logits_kernel(
    const float* __restrict__ Q, const float* __restrict__ K,
    const float* __restrict__ tempP, float* __restrict__ logits,
    float* __restrict__ Mpart, float* __restrict__ Spart) {
  __shared__ bf16_t qh[BM][LDK], ql[BM][LDK], kh[BN][LDK], kl[BN][LDK];
  __shared__ float ksred[BN][8];
  __shared__ float mred[BM][2], sred[BM][2];
  const int b = blockIdx.z;
  const int m0 = blockIdx.y * BM;
  const int n0 = blockIdx.x * BN;
  const int tid = threadIdx.x;
  const int lane = tid & 63;
  const int wave = tid >> 6;
  const int wm = (wave >> 1) * 64;
  const int wn = (wave & 1) * 64;
  const int lrow = lane & 15;
  const int quad = lane >> 4;

  const float* Qb = Q + (size_t)b * SQ * DD;
  const float* Kb = K + (size_t)b * SK * DD;

  const int srow = tid >> 3;        // 0..31
  const int scol = (tid & 7) * 4;   // 0,4,...,28

  const float* qbase = Qb + (size_t)(m0 + srow) * DD + scol;
  const float* kbase = Kb + (size_t)(n0 + srow) * DD + scol;

  f32x4 acc[4][4];
#pragma unroll
  for (int i = 0; i < 4; i++)
#pragma unroll
    for (int j = 0; j < 4; j++) acc[i][j] = (f32x4){0.f, 0.f, 0.f, 0.f};

  float kss[4] = {0.f, 0.f, 0.f, 0.f};

  float4 pq[4], pk[4];
#pragma unroll
  for (int i = 0; i < 4; i++) {
    pq[i] = *(const float4*)(qbase + (size_t)i * 32 * DD);
    pk[i] = *(const float4*)(kbase + (size_t)i * 32 * DD);
  }

  for (int k0 = 0; k0 < DD; k0 += BK) {
    __syncthreads();
#pragma unroll
    for (int i = 0; i < 4; i++) {
      const int r = srow + i * 32;
      float4 qv = pq[i], kv = pk[i];
      bf16_t q0 = (bf16_t)qv.x, q1 = (bf16_t)qv.y, q2 = (bf16_t)qv.z, q3 = (bf16_t)qv.w;
      bf16x4 qhv = {q0, q1, q2, q3};
      bf16x4 qlv = {(bf16_t)(qv.x - (float)q0), (bf16_t)(qv.y - (float)q1),
                    (bf16_t)(qv.z - (float)q2), (bf16_t)(qv.w - (float)q3)};
      bf16_t c0 = (bf16_t)kv.x, c1 = (bf16_t)kv.y, c2 = (bf16_t)kv.z, c3 = (bf16_t)kv.w;
      bf16x4 khv = {c0, c1, c2, c3};
      bf16x4 klv = {(bf16_t)(kv.x - (float)c0), (bf16_t)(kv.y - (float)c1),
                    (bf16_t)(kv.z - (float)c2), (bf16_t)(kv.w - (float)c3)};
      *(bf16x4*)&qh[r][scol] = qhv;
      *(bf16x4*)&ql[r][scol] = qlv;
      *(bf16x4*)&kh[r][scol] = khv;
      *(bf16x4*)&kl[r][scol] = klv;
      kss[i] = fmaf(kv.x, kv.x, kss[i]);
      kss[i] = fmaf(kv.y, kv.y, kss[i]);
      kss[i] = fmaf(kv.z, kv.z, kss[i]);
      kss[i] = fmaf(kv.w, kv.w, kss[i]);
    }
    __syncthreads();

    if (k0 + BK < DD) {
#pragma unroll
      for (int i = 0; i < 4; i++) {
        pq[i] = *(const float4*)(qbase + (size_t)i * 32 * DD + (k0 + BK));
        pk[i] = *(const float4*)(kbase + (size_t)i * 32 * DD + (k0 + BK));
      }
    }

    bf16x8 bh[4], bl[4];
#pragma unroll
    for (int ni = 0; ni < 4; ni++) {
      bh[ni] = *(const bf16x8*)&kh[wn + ni * 16 + lrow][quad * 8];
      bl[ni] = *(const bf16x8*)&kl[wn + ni * 16 + lrow][quad * 8];
    }
#pragma unroll
    for (int mi = 0; mi < 4; mi++) {
      bf16x8 ah = *(const bf16x8*)&qh[wm + mi * 16 + lrow][quad * 8];
      bf16x8 al = *(const bf16x8*)&ql[wm + mi * 16 + lrow][quad * 8];
#pragma unroll
      for (int ni = 0; ni < 4; ni++) {
        acc[mi][ni] = __builtin_amdgcn_mfma_f32_16x16x32_bf16(ah, bh[ni], acc[mi][ni], 0, 0, 0);
        acc[mi][ni] = __builtin_amdgcn_mfma_f32_16x16x32_bf16(ah, bl[ni], acc[mi][ni], 0, 0, 0);
        acc[mi][ni] = __builtin_amdgcn_mfma_f32_16x16x32_bf16(al, bh[ni], acc[mi][ni], 0, 0, 0);
      }
    }
  }

#pragma unroll
  for (int i = 0; i < 4; i++) ksred[srow + i * 32][tid & 7] = kss[i];
  __syncthreads();

  // base-2 pre-scale: logits' = (2 q.k - k^2) * log2(e)/T
  const float invT = 1.4426950408889634f / tempP[0];
  float* Lb = logits + (size_t)b * SQ * SK;
  float ks4[4];
#pragma unroll
  for (int ni = 0; ni < 4; ni++) {
    const float* kr = ksred[wn + ni * 16 + lrow];
    ks4[ni] = ((kr[0] + kr[1]) + (kr[2] + kr[3])) +
              ((kr[4] + kr[5]) + (kr[6] + kr[7]));
  }

#pragma unroll
  for (int mi = 0; mi < 4; mi++) {
#pragma unroll
    for (int r = 0; r < 4; r++) {
      const int row = wm + mi * 16 + quad * 4 + r;
      float sv[4];
#pragma unroll
      for (int ni = 0; ni < 4; ni++) {
        sv[ni] = (2.0f * acc[mi][ni][r] - ks4[ni]) * invT;
        Lb[(size_t)(m0 + row) * SK + (n0 + wn + ni * 16 + lrow)] = sv[ni];
      }
      float rm = fmaxf(fmaxf(sv[0], sv[1]), fmaxf(sv[2], sv[3]));
      rm = fmaxf(rm, __shfl_xor(rm, 1));
      rm = fmaxf(rm, __shfl_xor(rm, 2));
      rm = fmaxf(rm, __shfl_xor(rm, 4));
      rm = fmaxf(rm, __shfl_xor(rm, 8));
      float rs = exp2f(sv[0] - rm) + exp2f(sv[1] - rm) +
                 exp2f(sv[2] - rm) + exp2f(sv[3] - rm);
      rs += __shfl_xor(rs, 1);
      rs += __shfl_xor(rs, 2);
      rs += __shfl_xor(rs, 4);
      rs += __shfl_xor(rs, 8);
      if (lrow == 0) {
        mred[row][wave & 1] = rm;
        sred[row][wave & 1] = rs;
      }
    }
  }
  __syncthreads();
  if (tid < BM) {
    const float ma = mred[tid][0], mb = mred[tid][1];
    const float M = fmaxf(ma, mb);
    const float S = sred[tid][0] * exp2f(ma - M) + sred[tid][1] * exp2f(mb - M);
    const size_t o = ((size_t)b * NBLK + blockIdx.x) * SQ + (m0 + tid);
    Mpart[o] = M;
    Spart[o] = S;
  }
}

// ------------------------------------------------- Vt[b][d][k] bf16 = V^T
__global__ __launch_bounds__(256) void vt_kernel(const float* __restrict__ V,
                                                 bf16_t* __restrict__ Vt) {
  const int b = blockIdx.y;
  const int k0 = blockIdx.x * 32;
  const int tid = threadIdx.x;
  const int p = tid & 15;
  const int c = tid >> 4;
  const float* Vb = V + (size_t)b * SK * DD;
  bf16_t* Vtb = Vt + (size_t)b * DD * SK;
  const int k = k0 + 2 * p;
#pragma unroll
  for (int j = 0; j < 8; j++) {
    const int d0 = 4 * c + 64 * j;
    float4 v0 = *(const float4*)(Vb + (size_t)k * DD + d0);
    float4 v1 = *(const float4*)(Vb + (size_t)(k + 1) * DD + d0);
    bf16x2 t0 = {(bf16_t)v0.x, (bf16_t)v1.x};
    bf16x2 t1 = {(bf16_t)v0.y, (bf16_t)v1.y};
    bf16x2 t2 = {(bf16_t)v0.z, (bf16_t)v1.z};
    bf16x2 t3 = {(bf16_t)v0.w, (bf16_t)v1.w};
    *(bf16x2*)(Vtb + (size_t)(d0 + 0) * SK + k) = t0;
    *(bf16x2*)(Vtb + (size_t)(d0 + 1) * SK + k) = t1;
    *(bf16x2*)(Vtb + (size_t)(d0 + 2) * SK + k) = t2;
    *(bf16x2*)(Vtb + (size_t)(d0 + 3) * SK + k) = t3;
  }
}

// ------------------------------------------------- fused softmax + O = W @ V
// Chunked double-buffered panel. Block = 32 q-rows x all d, 512 thr, 8 waves.
// LDS: 2 x [32][256] bf16 chunks (32 KB) -> 2 blocks/CU (16 waves).
// Per chunk c: issue chunk c+1 raw-L loads -> GEMM chunk c (A from swizzled
// LDS, B per-wave from L2-resident Vt, 2-window prefetch carried across
// chunks) -> normalize c+1 (exp2), in-place W write, stage LDS -> lgkmcnt-
// only barrier (B prefetches stay in flight; only LDS visibility drained).
// Cross-block overlap (2/CU) hides phase-1 latency under phase-2 compute.
#define PM 32
#define CK 256                 // k-chunk elements
#define CKB 512                // chunk row bytes
#define NCH (SK / CK)          // 8 chunks
#define NWIN (SK / BK)         // 64 k-windows

__device__ __forceinline__ unsigned pv_lds(int row, unsigned kb) {
  return (unsigned)row * CKB + (kb ^ (unsigned)((row & 7) << 4));
}

__global__ __launch_bounds__(512, 4) void pv_kernel(
    float* __restrict__ L,               // raw logits in, weights out (in place)
    const bf16_t* __restrict__ Vt,
    const float* __restrict__ Mpart, const float* __restrict__ Spart,
    float* __restrict__ O) {
  __shared__ __align__(16) unsigned char wlds[2][PM * CKB];  // 2 x 16 KB
  __shared__ float Msh[PM], Ssh[PM];
  const int bid = blockIdx.x;
  const int b = bid & 7;            // XCD affinity: batch b -> XCD b
  const int m0 = (bid >> 3) * PM;
  const int tid = threadIdx.x;

  float* Lb = L + (size_t)b * SQ * SK;
  const bf16_t* Vtb = Vt + (size_t)b * DD * SK;

  // ---- combine base-2 split-softmax partials: 16 threads/row, 1 partial ea.
  {
    const int row = tid >> 4;       // 0..31
    const int j = tid & 15;
    const size_t o = ((size_t)b * NBLK + j) * SQ + (m0 + row);
    const float pm = Mpart[o];
    const float ps = Spart[o];
    float m = pm;
    m = fmaxf(m, __shfl_xor(m, 1));
    m = fmaxf(m, __shfl_xor(m, 2));
    m = fmaxf(m, __shfl_xor(m, 4));
    m = fmaxf(m, __shfl_xor(m, 8));
    float s = ps * exp2f(pm - m);
    s += __shfl_xor(s, 1);
    s += __shfl_xor(s, 2);
    s += __shfl_xor(s, 4);
    s += __shfl_xor(s, 8);
    if (j == 0) {
      Msh[row] = m;
      Ssh[row] = 1.0f / s;
    }
  }
  __syncthreads();

  // ---- staging identity: thread (prow, g) owns k = g*4 + j*64, j=0..3
  const int prow = tid >> 4;        // 0..31
  const int g = tid & 15;
  float* lp = Lb + (size_t)(m0 + prow) * SK;
  const float Mrow = Msh[prow];
  const float invS = Ssh[prow];

  auto stage = [&](const float4 (&pv4)[4], int c1) {
    unsigned char* buf = wlds[c1 & 1];
    const int kbase = c1 * CK;
#pragma unroll
    for (int j = 0; j < 4; j++) {
      const int k = g * 4 + j * 64;
      float4 v = pv4[j];
      const float w0 = exp2f(v.x - Mrow) * invS;
      const float w1 = exp2f(v.y - Mrow) * invS;
      const float w2 = exp2f(v.z - Mrow) * invS;
      const float w3 = exp2f(v.w - Mrow) * invS;
      *(float4*)(lp + kbase + k) = make_float4(w0, w1, w2, w3);  // W output
      bf16x4 w4 = {(bf16_t)w0, (bf16_t)w1, (bf16_t)w2, (bf16_t)w3};
      *(bf16x4*)(buf + pv_lds(prow, (unsigned)(k * 2))) = w4;
    }
  };

  // ---- GEMM identity
  const int lane = tid & 63;
  const int wave = tid >> 6;        // 0..7
  const int wn = wave * 64;
  const int lrow = lane & 15;
  const int quad = lane >> 4;

  const bf16_t* Brow[4];
#pragma unroll
  for (int ni = 0; ni < 4; ni++)
    Brow[ni] = Vtb + (size_t)(wn + ni * 16 + lrow) * SK + quad * 8;

  f32x4 acc[2][4];
#pragma unroll
  for (int i = 0; i < 2; i++)
#pragma unroll
    for (int j = 0; j < 4; j++) acc[i][j] = (f32x4){0.f, 0.f, 0.f, 0.f};

  // ---- prologue: stage chunk 0, prefetch B windows 0,1
  {
    float4 p0[4];
#pragma unroll
    for (int j = 0; j < 4; j++) p0[j] = *(const float4*)(lp + g * 4 + j * 64);
    stage(p0, 0);
  }
  bf16x8 bw[2][4];
#pragma unroll
  for (int ni = 0; ni < 4; ni++) bw[0][ni] = *(const bf16x8*)(Brow[ni]);
#pragma unroll
  for (int ni = 0; ni < 4; ni++) bw[1][ni] = *(const bf16x8*)(Brow[ni] + BK);
  __syncthreads();

  for (int c = 0; c < NCH; c++) {
    // issue next chunk's raw-L loads (latency hides under this chunk's GEMM)
    float4 pn[4];
    if (c + 1 < NCH) {
      const int kbase = (c + 1) * CK;
#pragma unroll
      for (int j = 0; j < 4; j++)
        pn[j] = *(const float4*)(lp + kbase + g * 4 + j * 64);
    }

    // GEMM over this chunk's 8 windows; B prefetch 2 windows ahead (global k)
    const unsigned char* buf = wlds[c & 1];
#pragma unroll
    for (int w = 0; w < CK / BK; w++) {
      const int gw = c * (CK / BK) + w;
      bf16x8 a0 = *(const bf16x8*)(buf + pv_lds(lrow, (unsigned)(w * 64 + quad * 16)));
      bf16x8 a1 = *(const bf16x8*)(buf + pv_lds(16 + lrow, (unsigned)(w * 64 + quad * 16)));
#pragma unroll
      for (int ni = 0; ni < 4; ni++)
        acc[0][ni] = __builtin_amdgcn_mfma_f32_16x16x32_bf16(a0, bw[gw & 1][ni],
                                                             acc[0][ni], 0, 0, 0);
#pragma unroll
      for (int ni = 0; ni < 4; ni++)
        acc[1][ni] = __builtin_amdgcn_mfma_f32_16x16x32_bf16(a1, bw[gw & 1][ni],
                                                             acc[1][ni], 0, 0, 0);
      if (gw + 2 < NWIN) {
#pragma unroll
        for (int ni = 0; ni < 4; ni++)
          bw[gw & 1][ni] = *(const bf16x8*)(Brow[ni] + (gw + 2) * BK);
      }
    }

    if (c + 1 < NCH) {
      stage(pn, c + 1);  // compiler inserts vmcnt wait on pn use
      // LDS-visibility-only barrier: B prefetches + W writes stay in flight
      asm volatile("s_waitcnt lgkmcnt(0)\n\ts_barrier" ::: "memory");
    }
  }

  float* Ob = O + (size_t)b * SQ * DD;
#pragma unroll
  for (int ni = 0; ni < 4; ni++) {
    const int d = wn + ni * 16 + lrow;
#pragma unroll
    for (int mi = 0; mi < 2; mi++) {
      const int mbase = m0 + mi * 16 + quad * 4;
#pragma unroll
      for (int r = 0; r < 4; r++) {
        Ob[(size_t)(mbase + r) * DD + d] = acc[mi][ni][r];
      }
    }
  }
}

extern "C" void kernel_launch(void* const* d_in, const int* in_sizes, int n_in,
                              void* d_out, int out_size, void* d_ws, size_t ws_size,
                              hipStream_t stream) {
  const float* Q = (const float*)d_in[0];
  const float* K = (const float*)d_in[1];
  const float* V = (const float*)d_in[2];
  const float* T = (const float*)d_in[3];

  float* outv = (float*)d_out;                          // [8,2048,512]
  float* logits = outv + (size_t)NB * SQ * DD;          // [8,2048,2048] weights region

  // workspace: softmax partials (2 MB) + Vt bf16 (16.8 MB)
  float* Mpart = (float*)d_ws;
  float* Spart = Mpart + (size_t)NB * NBLK * SQ;
  bf16_t* Vt = (bf16_t*)(Spart + (size_t)NB * NBLK * SQ);

  vt_kernel<<<dim3(SK / 32, NB), 256, 0, stream>>>(V, Vt);
  logits_kernel<<<dim3(SK / BN, SQ / BM, NB), 256, 0, stream>>>(Q, K, T, logits,
                                                                Mpart, Spart);
  pv_kernel<<<dim3(NB * (SQ / PM)), 512, 0, stream>>>(logits, Vt, Mpart, Spart, outv);
}